// Round 15
// baseline (196.124 us; speedup 1.0000x reference)
//
#include <hip/hip_runtime.h>

// SHGR kNN head: cosine distance, top-16, inverse-distance weighted target average.
// B=2048, N=100000, D=128, T=8, k=16.
//
// Pipeline (5 dispatches):
//   1. norm_rows_k (fused): L2-normalize supports AND queries -> bf16 in ws.
//   2. pass1_k: transposed 32x32x16 bf16 MFMA (D[support][query]; lane holds 16
//      supports x 1 query). Per-(query,16-support sub) max: rows 0-15 = regs
//      r<8, rows 16-31 = regs r>=8 (lo/hi split is register-local), so each
//      16-row submax costs 7 fmax + 1 shfl. cm [q/4][gs][q%4], bf16 down-rnd.
//   3. thr_k: thr[q] = (16th-largest of 6400 sub-maxes) - 0.013 margin; zeroes
//      cnt[q]. [16 subs >= t => 16 distinct supports >= t => t <= s16; margin
//      covers bf16 score error (<=2.5e-3) 5x; E[cands] ~ 27/query]
//   4. pass2_k: visit hit 16-row subs only (stored max >= thr), 4 subs per
//      staged 64-row tile, recompute scores (bitwise-identical 32x32 MFMA),
//      emit >= thr to per-query global list (cap 64).
//   5. merge_refine_k: 4 queries/block; exact (f64) refine ALL ~27 cands,
//      bitonic top-16 -> weights -> gather targets -> out.
//
// NOTE (R7): update_dpp row_ror gave wrong submaxes on gfx950 -> shfl_xor only.
// NOTE (R10/R11): grid 1024 = 4 blk/CU; higher/lower occupancy variants lose.
// NOTE (R13): counted-vmcnt null -> plain __syncthreads.
// NOTE (R14): 32-row hit granularity inflated pass2's block hit-union 42->66%
// of subs (+57% rows recomputed); this version restores 16-row granularity.
// LDS swizzle ^(row&15): SQ_LDS_BANK_CONFLICT == 0 measured (R14).

#define NSLICES 64
#define CN 64
#define BQ 128
#define NSUB 100                 // subs per slice = 25 chunks * 4 (16-row subs)
#define NGS (NSLICES * NSUB)     // 6400 subs per query
#define QCAP 64                  // per-query candidate list; E=27, P(>64)~1e-9
#define THR_MARGIN 0.013f

typedef __bf16 bf16x8 __attribute__((ext_vector_type(8)));
typedef float f32x16 __attribute__((ext_vector_type(16)));

__device__ __forceinline__ ushort f2bf_rne(float f) {
  unsigned u = __float_as_uint(f);
  return (ushort)((u + 0x7FFFu + ((u >> 16) & 1u)) >> 16);
}
// round toward -inf in bf16 (stored max <= true max)
__device__ __forceinline__ ushort f2bf_down(float f) {
  unsigned u = __float_as_uint(f);
  return (ushort)((u >> 16) + (u >> 31));
}
__device__ __forceinline__ unsigned bf2key(ushort b) {
  return (unsigned)(b ^ ((b & 0x8000u) ? 0xFFFFu : 0x8000u));
}

// Full-wave bitonic sort, ascending in (v, i) lexicographic.
__device__ __forceinline__ void bitonic64(float& v, unsigned& i, int lane) {
  #pragma unroll
  for (int k = 2; k <= 64; k <<= 1) {
    #pragma unroll
    for (int j = k >> 1; j > 0; j >>= 1) {
      float pv = __shfl_xor(v, j);
      unsigned pi = (unsigned)__shfl_xor((int)i, j);
      bool up = ((lane & k) == 0);
      bool lower = ((lane & j) == 0);
      bool gt = (v > pv) || (v == pv && i > pi);
      bool keep = (up == lower) ? !gt : gt;
      if (!keep) { v = pv; i = pi; }
    }
  }
}

// Fused: rows [0,N) = supports -> sb; rows [N, N+nq) = queries -> qb.
__global__ __launch_bounds__(256) void norm_rows_k(
    const float* __restrict__ sup, const float* __restrict__ qry,
    ushort* __restrict__ sb, ushort* __restrict__ qb, int N, int nq) {
  int row = blockIdx.x * 4 + (threadIdx.x >> 6);
  int lane = threadIdx.x & 63;
  if (row >= N + nq) return;
  const float* src = (row < N) ? (sup + (size_t)row * 128)
                               : (qry + (size_t)(row - N) * 128);
  ushort* dst = (row < N) ? (sb + (size_t)row * 128)
                          : (qb + (size_t)(row - N) * 128);
  float2 v = *reinterpret_cast<const float2*>(src + lane * 2);
  float ss = v.x * v.x + v.y * v.y;
  #pragma unroll
  for (int o = 1; o < 64; o <<= 1) ss += __shfl_xor(ss, o);
  float inv = 1.0f / fmaxf(sqrtf(ss), 1e-12f);
  ushort2 h = make_ushort2(f2bf_rne(v.x * inv), f2bf_rne(v.y * inv));
  *reinterpret_cast<ushort2*>(dst + lane * 2) = h;
}

// Stage 64x128 bf16 chunk: linear LDS dest + inverse-swizzled (^row&15) source.
__device__ __forceinline__ void stage_lin(const ushort* __restrict__ sn,
                                          ushort* dst, int cb, int s1, int tid) {
  #pragma unroll
  for (int r = 0; r < 4; ++r) {
    int o = (r << 12) + tid * 16;
    int row = o >> 8;
    int dj = (o >> 4) & 15;
    int sj = dj ^ (row & 15);
    int srow = min(cb + row, s1 - 1);
    __builtin_amdgcn_global_load_lds(
        (const unsigned int*)(sn + (size_t)srow * 128 + sj * 8),
        (unsigned int*)(dst + (o >> 1)), 16, 0, 0);
  }
}

// Stage a gathered batch of 4 subs (16 rows each) from slist.
__device__ __forceinline__ void stage_list(const ushort* __restrict__ sn,
                                           ushort* dst, const ushort* slist_b,
                                           int s0, int s1, int tid) {
  #pragma unroll
  for (int r = 0; r < 4; ++r) {
    int o = (r << 12) + tid * 16;
    int row = o >> 8;
    int dj = (o >> 4) & 15;
    int sj = dj ^ (row & 15);
    int sub = slist_b[row >> 4];
    int lrow = (sub == 0xFFFF) ? 0 : sub * 16 + (row & 15);
    int srow = min(s0 + lrow, s1 - 1);
    __builtin_amdgcn_global_load_lds(
        (const unsigned int*)(sn + (size_t)srow * 128 + sj * 8),
        (unsigned int*)(dst + (o >> 1)), 16, 0, 0);
  }
}

// Pass 1: 16-row sub maxes. 1024 blocks XCD-decoded (8 slices/XCD).
// 32x32x16 MFMA, D[row=support][col=query]: lane = query (lane&31) x 16 rows.
__global__ __launch_bounds__(256, 4) void pass1_k(
    const ushort* __restrict__ qn, const ushort* __restrict__ sn,
    ushort* __restrict__ cm, int N) {
  __shared__ ushort st[2][CN * 128];
  const int tid = threadIdx.x;
  const int w = tid >> 6, lane = tid & 63;
  const int q32 = lane & 31, half = lane >> 5;
  const int L = blockIdx.x;             // 1024 = 8 xcd * (16 qtile * 8 slice)
  const int xcd = L & 7, i6 = L >> 3;
  const int qtile = i6 & 15;
  const int slice = (xcd << 3) | (i6 >> 4);
  const int qbase = qtile * BQ;
  const int SLICE = (N + NSLICES - 1) / NSLICES;  // 1563
  const int s0 = slice * SLICE;
  const int s1 = min(N, s0 + SLICE);
  const int nch = (s1 - s0 + CN - 1) / CN;  // 25 (24 for last slice)

  stage_lin(sn, &st[0][0], s0, s1, tid);

  // Query fragments (B operand): col = lane&31, k = half*8 + e per 16-k step.
  bf16x8 afr[8];
  {
    const int qrow = qbase + w * 32 + q32;
    #pragma unroll
    for (int t = 0; t < 8; ++t)
      afr[t] = *reinterpret_cast<const bf16x8*>(qn + (size_t)qrow * 128 + t * 16 + half * 8);
  }
  __syncthreads();

  int buf = 0;
  for (int ch = 0; ch < nch; ++ch) {
    const int cb = s0 + ch * CN;
    if (ch + 1 < nch) stage_lin(sn, &st[buf ^ 1][0], cb + CN, s1, tid);
    const ushort* stc = &st[buf][0];
    const bool lastch = (ch == nch - 1);

    f32x16 a0 = {0.f}, a1 = {0.f};
    #pragma unroll
    for (int r = 1; r < 16; ++r) { a0[r] = 0.f; a1[r] = 0.f; }
    const int r0 = q32;                  // A row within tile = lane&31
    #pragma unroll
    for (int t = 0; t < 8; ++t) {
      int jb = t * 2 + half;             // 16B block in row
      int cj = jb ^ (r0 & 15);           // rows r0 and r0+32 share (row&15)
      bf16x8 sf0 = *reinterpret_cast<const bf16x8*>(&stc[r0 * 128 + cj * 8]);
      bf16x8 sf1 = *reinterpret_cast<const bf16x8*>(&stc[(r0 + 32) * 128 + cj * 8]);
      a0 = __builtin_amdgcn_mfma_f32_32x32x16_bf16(sf0, afr[t], a0, 0, 0, 0);
      a1 = __builtin_amdgcn_mfma_f32_32x32x16_bf16(sf1, afr[t], a1, 0, 0, 0);
    }
    // lo/hi 16-row submaxes per tile: rows = (r&3)+8*(r>>2)+(half<<2);
    // r<8 -> rows 0..15 (union over halves), r>=8 -> rows 16..31.
    float v0lo = -3.0e38f, v0hi = -3.0e38f, v1lo = -3.0e38f, v1hi = -3.0e38f;
    #pragma unroll
    for (int r = 0; r < 8; ++r) {
      int row = (r & 3) + 8 * (r >> 2) + (half << 2);   // 0..15
      int rowh = row + 16;
      if (!lastch || cb + row < s1) v0lo = fmaxf(v0lo, a0[r]);
      if (!lastch || cb + rowh < s1) v0hi = fmaxf(v0hi, a0[r + 8]);
      if (!lastch || cb + 32 + row < s1) v1lo = fmaxf(v1lo, a1[r]);
      if (!lastch || cb + 32 + rowh < s1) v1hi = fmaxf(v1hi, a1[r + 8]);
    }
    v0lo = fmaxf(v0lo, __shfl_xor(v0lo, 32));
    v0hi = fmaxf(v0hi, __shfl_xor(v0hi, 32));
    v1lo = fmaxf(v1lo, __shfl_xor(v1lo, 32));
    v1hi = fmaxf(v1hi, __shfl_xor(v1hi, 32));
    if (lane < 32) {                     // 32 lanes store 2B x 4 subs
      int q = qbase + w * 32 + q32;
      size_t e0 = ((size_t)(q >> 2) * NGS + slice * NSUB + ch * 4) * 4 + (q & 3);
      cm[e0] = f2bf_down(v0lo);          // sub ch*4+0: rows cb+0..15
      cm[e0 + 4] = f2bf_down(v0hi);      // sub ch*4+1: rows cb+16..31
      cm[e0 + 8] = f2bf_down(v1lo);      // sub ch*4+2: rows cb+32..47
      cm[e0 + 12] = f2bf_down(v1hi);     // sub ch*4+3: rows cb+48..63
    }
    __syncthreads();
    buf ^= 1;
  }

  // fill unwritten tail subs (nch < 25 on the last slice) with bf16 -inf
  const int miss = NSUB - nch * 4;
  for (int idx = tid; idx < miss * BQ; idx += 256) {
    int sub = nch * 4 + idx / BQ;
    int q = qbase + (idx % BQ);
    cm[((size_t)(q >> 2) * NGS + (size_t)(slice * NSUB + sub)) * 4 + (q & 3)] = 0xFF80;
  }
}

// thr[q] = 16th-largest of the 6400 sub-maxes, minus margin; zero cnt[q].
// 4 queries per 256-thread block (one per wave).
__global__ __launch_bounds__(256) void thr_k(const ushort* __restrict__ cm,
                                             float* __restrict__ thr,
                                             unsigned* __restrict__ cnt) {
  const int q = blockIdx.x * 4 + (threadIdx.x >> 6);
  const int lane = threadIdx.x & 63;
  const size_t base = (size_t)(q >> 2) * NGS * 4 + (q & 3);
  unsigned keys[NGS / 128];
  #pragma unroll
  for (int j = 0; j < NGS / 128; ++j) {
    unsigned k0 = bf2key(cm[base + (size_t)(lane + 128 * j) * 4]);
    unsigned k1 = bf2key(cm[base + (size_t)(lane + 64 + 128 * j) * 4]);
    keys[j] = k0 | (k1 << 16);
  }
  unsigned res = 0;
  for (int b = 15; b >= 0; --b) {
    unsigned t = res | (1u << b);
    int c = 0;
    #pragma unroll
    for (int j = 0; j < NGS / 128; ++j)
      c += (int)((keys[j] & 0xFFFFu) >= t) + (int)((keys[j] >> 16) >= t);
    #pragma unroll
    for (int o = 1; o < 64; o <<= 1) c += __shfl_xor(c, o);
    if (c >= 16) res = t;
  }
  if (lane == 0) {
    ushort b16 = (ushort)((res & 0x8000u) ? (res ^ 0x8000u) : (res ^ 0xFFFFu));
    thr[q] = __uint_as_float((unsigned)b16 << 16) - THR_MARGIN;
    cnt[q] = 0;
  }
}

// Pass 2: visit only hit 16-row subs (stored max >= thr), 4 per staged batch.
// 32x32x16 MFMA: lane = 1 query x 16 supports; thr per lane hoisted.
__global__ __launch_bounds__(256, 4) void pass2_k(
    const ushort* __restrict__ qn, const ushort* __restrict__ sn,
    const ushort* __restrict__ cm, const float* __restrict__ thr,
    unsigned* __restrict__ cnt, float2* __restrict__ candq, int N) {
  __shared__ ushort st[2][CN * 128];
  __shared__ float thr_l[BQ];
  __shared__ unsigned char hit[NSUB];
  __shared__ ushort slist[NSUB + 4];
  __shared__ int nhit_s;

  const int tid = threadIdx.x;
  const int w = tid >> 6, lane = tid & 63;
  const int q32 = lane & 31, half = lane >> 5;
  const int L = blockIdx.x;
  const int xcd = L & 7, i6 = L >> 3;
  const int qtile = i6 & 15;
  const int slice = (xcd << 3) | (i6 >> 4);
  const int qbase = qtile * BQ;
  const int SLICE = (N + NSLICES - 1) / NSLICES;
  const int s0 = slice * SLICE;
  const int s1 = min(N, s0 + SLICE);
  const int slen = s1 - s0;

  if (tid < BQ) thr_l[tid] = thr[qbase + tid];
  if (tid < NSUB) hit[tid] = 0;
  __syncthreads();

  // hit scan: thread (q = tid&127, parity = tid>>7) covers s = 2j+parity
  {
    int q = qbase + (tid & 127);
    int sh = tid >> 7;
    float tq = thr_l[tid & 127];
    size_t base = (size_t)(q >> 2) * NGS * 4 + (q & 3);
    for (int j = 0; j < NSUB / 2; ++j) {
      int s = 2 * j + sh;
      ushort b = cm[base + (size_t)(slice * NSUB + s) * 4];
      if (__uint_as_float((unsigned)b << 16) >= tq) hit[s] = 1;
    }
  }
  __syncthreads();
  // compact hit subs (wave 0; NSUB=100 -> two ballot rounds)
  if (tid < 64) {
    int total = 0;
    #pragma unroll
    for (int r = 0; r < 2; ++r) {
      int idx = r * 64 + tid;
      bool f = (idx < NSUB) && hit[idx];
      unsigned long long bm = __ballot(f);
      int pos = total + __popcll(bm & ((1ull << tid) - 1ull));
      if (f) slist[pos] = (ushort)idx;
      total += __popcll(bm);
    }
    if (tid == 0) {
      nhit_s = total;
      #pragma unroll
      for (int p = 0; p < 4; ++p) slist[total + p] = 0xFFFF;
    }
  }
  __syncthreads();
  const int nhit = nhit_s;
  if (nhit == 0) return;
  const int nb = (nhit + 3) >> 2;

  bf16x8 afr[8];
  {
    const int qrow = qbase + w * 32 + q32;
    #pragma unroll
    for (int t = 0; t < 8; ++t)
      afr[t] = *reinterpret_cast<const bf16x8*>(qn + (size_t)qrow * 128 + t * 16 + half * 8);
  }
  const float thrq = thr_l[w * 32 + q32];

  stage_list(sn, &st[0][0], &slist[0], s0, s1, tid);
  __syncthreads();

  int buf = 0;
  for (int b = 0; b < nb; ++b) {
    if (b + 1 < nb) stage_list(sn, &st[buf ^ 1][0], &slist[(b + 1) * 4], s0, s1, tid);
    const ushort* stc = &st[buf][0];

    f32x16 a0 = {0.f}, a1 = {0.f};
    #pragma unroll
    for (int r = 1; r < 16; ++r) { a0[r] = 0.f; a1[r] = 0.f; }
    const int r0 = q32;
    #pragma unroll
    for (int t = 0; t < 8; ++t) {
      int jb = t * 2 + half;
      int cj = jb ^ (r0 & 15);
      bf16x8 sf0 = *reinterpret_cast<const bf16x8*>(&stc[r0 * 128 + cj * 8]);
      bf16x8 sf1 = *reinterpret_cast<const bf16x8*>(&stc[(r0 + 32) * 128 + cj * 8]);
      a0 = __builtin_amdgcn_mfma_f32_32x32x16_bf16(sf0, afr[t], a0, 0, 0, 0);
      a1 = __builtin_amdgcn_mfma_f32_32x32x16_bf16(sf1, afr[t], a1, 0, 0, 0);
    }
    const int q = qbase + w * 32 + q32;
    // tile A = staged rows 0..31 (subs slist[4b], slist[4b+1]);
    // tile B = staged rows 32..63 (subs slist[4b+2], slist[4b+3]).
    #pragma unroll
    for (int tile = 0; tile < 2; ++tile) {
      unsigned hm = 0;
      #pragma unroll
      for (int r = 0; r < 16; ++r) {
        int row = (r & 3) + 8 * (r >> 2) + (half << 2);   // 0..31 within tile
        int sub = slist[b * 4 + tile * 2 + (row >> 4)];
        int lrow = row & 15;
        float sc = tile ? a1[r] : a0[r];
        if (sub != 0xFFFF && sub * 16 + lrow < slen && sc >= thrq) hm |= 1u << r;
      }
      if (__any(hm != 0u)) {
        #pragma unroll
        for (int r = 0; r < 16; ++r) {
          if (hm & (1u << r)) {
            int row = (r & 3) + 8 * (r >> 2) + (half << 2);
            int sub = slist[b * 4 + tile * 2 + (row >> 4)];
            int lrow = row & 15;
            float sc = tile ? a1[r] : a0[r];
            unsigned p = atomicAdd(&cnt[q], 1u);
            if (p < (unsigned)QCAP)
              candq[(size_t)q * QCAP + p] =
                  make_float2(sc, __int_as_float(s0 + sub * 16 + lrow));
          }
        }
      }
    }
    __syncthreads();
    buf ^= 1;
  }
}

// 4 queries per 256-thread block (one wave each): gather ~27 candidates,
// exact (f64) refine ALL, bitonic top-16 (tie: lower idx) -> weights -> out.
__global__ __launch_bounds__(256) void merge_refine_k(
    const float* __restrict__ query, const float* __restrict__ supports,
    const float* __restrict__ targets, const unsigned* __restrict__ cnt,
    const float2* __restrict__ candq, float* __restrict__ out) {
  const int W = threadIdx.x >> 6;
  const int q = blockIdx.x * 4 + W;
  const int lane = threadIdx.x & 63;
  __shared__ float qh_s[4][128];
  __shared__ float2 list[4][QCAP];
  __shared__ float2 refd[4][QCAP];

  int total = min((int)cnt[q], QCAP);
  if (lane < total) list[W][lane] = candq[(size_t)q * QCAP + lane];

  float2 qv = *reinterpret_cast<const float2*>(query + (size_t)q * 128 + lane * 2);
  double qss = (double)qv.x * qv.x + (double)qv.y * qv.y;
  #pragma unroll
  for (int o = 1; o < 64; o <<= 1) qss += __shfl_xor(qss, o);
  float qn1 = fmaxf((float)sqrt(qss), 1e-12f);
  qh_s[W][lane * 2] = qv.x / qn1;
  qh_s[W][lane * 2 + 1] = qv.y / qn1;
  __syncthreads();

  const int g16 = lane >> 4, m16 = lane & 15;
  float qh[8];
  #pragma unroll
  for (int d = 0; d < 8; ++d) qh[d] = qh_s[W][m16 * 8 + d];
  int rounds = (total + 3) >> 2;
  for (int r = 0; r < rounds; ++r) {
    int cc = r * 4 + g16;
    bool valid = cc < total;
    float2 ce = valid ? list[W][cc] : make_float2(0.f, __int_as_float(0));
    int sidx = __float_as_int(ce.y);
    float4 sa = *reinterpret_cast<const float4*>(supports + (size_t)sidx * 128 + m16 * 8);
    float4 sb = *reinterpret_cast<const float4*>(supports + (size_t)sidx * 128 + m16 * 8 + 4);
    float sv[8] = {sa.x, sa.y, sa.z, sa.w, sb.x, sb.y, sb.z, sb.w};
    double ss = 0.0, dt = 0.0;
    #pragma unroll
    for (int d = 0; d < 8; ++d) {
      ss += (double)sv[d] * sv[d];
      dt += (double)qh[d] * sv[d];
    }
    #pragma unroll
    for (int o = 1; o < 16; o <<= 1) {
      ss += __shfl_xor(ss, o);
      dt += __shfl_xor(dt, o);
    }
    if (m16 == 0 && valid) {
      float sn1 = fmaxf((float)sqrt(ss), 1e-12f);
      refd[W][cc] = make_float2((float)(1.0 - dt / (double)sn1), ce.y);
    }
  }
  __syncthreads();

  float dv = (lane < total) ? refd[W][lane].x : 3.0e38f;
  unsigned di = (lane < total) ? (unsigned)__float_as_int(refd[W][lane].y) : 0xFFFFFFFFu;
  bitonic64(dv, di, lane);  // ascending (d, idx): lanes 0..15 = top-16

  float wv = (lane < 16) ? 1.0f / (dv + 1e-8f) : 0.0f;
  float wsum = wv;
  #pragma unroll
  for (int o = 1; o < 64; o <<= 1) wsum += __shfl_xor(wsum, o);
  float acc[8];
  #pragma unroll
  for (int t = 0; t < 8; ++t) acc[t] = 0.f;
  if (lane < 16) {
    float wn = wv / wsum;
    const float* tp = targets + (size_t)di * 8;
    #pragma unroll
    for (int t = 0; t < 8; ++t) acc[t] = wn * tp[t];
  }
  #pragma unroll
  for (int o = 1; o < 16; o <<= 1) {
    #pragma unroll
    for (int t = 0; t < 8; ++t) acc[t] += __shfl_xor(acc[t], o);
  }
  if (lane == 0) {
    #pragma unroll
    for (int t = 0; t < 8; ++t) out[(size_t)q * 8 + t] = acc[t];
  }
}

extern "C" void kernel_launch(void* const* d_in, const int* in_sizes, int n_in,
                              void* d_out, int out_size, void* d_ws, size_t ws_size,
                              hipStream_t stream) {
  const float* query = (const float*)d_in[0];
  const float* supports = (const float*)d_in[1];
  const float* targets = (const float*)d_in[2];
  float* out = (float*)d_out;
  const int D = 128;
  const int B = in_sizes[0] / D;   // 2048
  const int N = in_sizes[1] / D;   // 100000

  char* ws = (char*)d_ws;
  size_t off = 0;
  ushort* sn = (ushort*)(ws + off); off += (size_t)N * D * 2;
  off = (off + 255) & ~(size_t)255;
  ushort* qn = (ushort*)(ws + off); off += (size_t)B * D * 2;
  off = (off + 255) & ~(size_t)255;
  ushort* cm = (ushort*)(ws + off); off += (size_t)B * NGS * 2;        // 26.2MB
  off = (off + 255) & ~(size_t)255;
  float* thr = (float*)(ws + off); off += (size_t)B * 4;
  off = (off + 255) & ~(size_t)255;
  unsigned* cnt = (unsigned*)(ws + off); off += (size_t)B * 4;
  off = (off + 255) & ~(size_t)255;
  float2* candq = (float2*)(ws + off); off += (size_t)B * QCAP * sizeof(float2);
  if (off > ws_size) return;

  hipLaunchKernelGGL(norm_rows_k, dim3((N + B + 3) / 4), dim3(256), 0, stream,
                     supports, query, sn, qn, N, B);
  int nblk = (B / BQ) * NSLICES;  // 1024
  hipLaunchKernelGGL(pass1_k, dim3(nblk), dim3(256), 0, stream, qn, sn, cm, N);
  hipLaunchKernelGGL(thr_k, dim3(B / 4), dim3(256), 0, stream, cm, thr, cnt);
  hipLaunchKernelGGL(pass2_k, dim3(nblk), dim3(256), 0, stream, qn, sn, cm, thr, cnt, candq, N);
  hipLaunchKernelGGL(merge_refine_k, dim3(B / 4), dim3(256), 0, stream, query, supports, targets, cnt, candq, out);
}

// Round 16
// 181.986 us; speedup vs baseline: 1.0777x; 1.0777x over previous
//
#include <hip/hip_runtime.h>

// SHGR kNN head: cosine distance, top-16, inverse-distance weighted target average.
// B=2048, N=100000, D=128, T=8, k=16.
//
// Pipeline (5 dispatches):
//   1. norm_rows_k (fused): L2-normalize supports AND queries -> bf16 in ws.
//   2. pass1_k: transposed 32x32x16 bf16 MFMA (D[support][query]; lane holds 16
//      supports x 1 query). Per-(query,16-row sub) max via lo/hi register
//      split: fast path (all but last chunk) = 28 unconditional fmax + 4 shfl;
//      masked path only on the last chunk (R15 regression: the mask test inside
//      the loop cost 29us of pure VALU). cm [q/4][gs][q%4], bf16 down-rounded.
//   3. thr_k: thr[q] = (16th-largest of 6400 sub-maxes) - 0.013 margin; zeroes
//      cnt[q]. [16 subs >= t => 16 distinct supports >= t => t <= s16; margin
//      covers bf16 score error (<=2.5e-3) 5x; E[cands] ~ 27/query]
//   4. pass2_k: visit hit 16-row subs only (stored max >= thr), 4 subs per
//      staged 64-row tile, recompute scores (bitwise-identical 32x32 MFMA),
//      emit >= thr to per-query global list (cap 64).
//   5. merge_refine_k: 4 queries/block; exact (f64) refine ALL ~27 cands,
//      bitonic top-16 -> weights -> gather targets -> out.
//
// NOTE (R7): update_dpp row_ror gave wrong submaxes on gfx950 -> shfl_xor only.
// NOTE (R10/R11): grid 1024 = 4 blk/CU; higher/lower occupancy variants lose.
// NOTE (R13): counted-vmcnt null -> plain __syncthreads.
// NOTE (R14): 32-row hit granularity inflated pass2 (+57% rows recomputed).
// NOTE (R15): per-element lastch mask = +100 VALU/chunk -> hoist the branch.
// LDS swizzle ^(row&15): SQ_LDS_BANK_CONFLICT == 0 measured (R14/R15).

#define NSLICES 64
#define CN 64
#define BQ 128
#define NSUB 100                 // subs per slice = 25 chunks * 4 (16-row subs)
#define NGS (NSLICES * NSUB)     // 6400 subs per query
#define QCAP 64                  // per-query candidate list; E=27, P(>64)~1e-9
#define THR_MARGIN 0.013f

typedef __bf16 bf16x8 __attribute__((ext_vector_type(8)));
typedef float f32x16 __attribute__((ext_vector_type(16)));

__device__ __forceinline__ ushort f2bf_rne(float f) {
  unsigned u = __float_as_uint(f);
  return (ushort)((u + 0x7FFFu + ((u >> 16) & 1u)) >> 16);
}
// round toward -inf in bf16 (stored max <= true max)
__device__ __forceinline__ ushort f2bf_down(float f) {
  unsigned u = __float_as_uint(f);
  return (ushort)((u >> 16) + (u >> 31));
}
__device__ __forceinline__ unsigned bf2key(ushort b) {
  return (unsigned)(b ^ ((b & 0x8000u) ? 0xFFFFu : 0x8000u));
}

// Full-wave bitonic sort, ascending in (v, i) lexicographic.
__device__ __forceinline__ void bitonic64(float& v, unsigned& i, int lane) {
  #pragma unroll
  for (int k = 2; k <= 64; k <<= 1) {
    #pragma unroll
    for (int j = k >> 1; j > 0; j >>= 1) {
      float pv = __shfl_xor(v, j);
      unsigned pi = (unsigned)__shfl_xor((int)i, j);
      bool up = ((lane & k) == 0);
      bool lower = ((lane & j) == 0);
      bool gt = (v > pv) || (v == pv && i > pi);
      bool keep = (up == lower) ? !gt : gt;
      if (!keep) { v = pv; i = pi; }
    }
  }
}

// Fused: rows [0,N) = supports -> sb; rows [N, N+nq) = queries -> qb.
__global__ __launch_bounds__(256) void norm_rows_k(
    const float* __restrict__ sup, const float* __restrict__ qry,
    ushort* __restrict__ sb, ushort* __restrict__ qb, int N, int nq) {
  int row = blockIdx.x * 4 + (threadIdx.x >> 6);
  int lane = threadIdx.x & 63;
  if (row >= N + nq) return;
  const float* src = (row < N) ? (sup + (size_t)row * 128)
                               : (qry + (size_t)(row - N) * 128);
  ushort* dst = (row < N) ? (sb + (size_t)row * 128)
                          : (qb + (size_t)(row - N) * 128);
  float2 v = *reinterpret_cast<const float2*>(src + lane * 2);
  float ss = v.x * v.x + v.y * v.y;
  #pragma unroll
  for (int o = 1; o < 64; o <<= 1) ss += __shfl_xor(ss, o);
  float inv = 1.0f / fmaxf(sqrtf(ss), 1e-12f);
  ushort2 h = make_ushort2(f2bf_rne(v.x * inv), f2bf_rne(v.y * inv));
  *reinterpret_cast<ushort2*>(dst + lane * 2) = h;
}

// Stage 64x128 bf16 chunk: linear LDS dest + inverse-swizzled (^row&15) source.
__device__ __forceinline__ void stage_lin(const ushort* __restrict__ sn,
                                          ushort* dst, int cb, int s1, int tid) {
  #pragma unroll
  for (int r = 0; r < 4; ++r) {
    int o = (r << 12) + tid * 16;
    int row = o >> 8;
    int dj = (o >> 4) & 15;
    int sj = dj ^ (row & 15);
    int srow = min(cb + row, s1 - 1);
    __builtin_amdgcn_global_load_lds(
        (const unsigned int*)(sn + (size_t)srow * 128 + sj * 8),
        (unsigned int*)(dst + (o >> 1)), 16, 0, 0);
  }
}

// Stage a gathered batch of 4 subs (16 rows each) from slist.
__device__ __forceinline__ void stage_list(const ushort* __restrict__ sn,
                                           ushort* dst, const ushort* slist_b,
                                           int s0, int s1, int tid) {
  #pragma unroll
  for (int r = 0; r < 4; ++r) {
    int o = (r << 12) + tid * 16;
    int row = o >> 8;
    int dj = (o >> 4) & 15;
    int sj = dj ^ (row & 15);
    int sub = slist_b[row >> 4];
    int lrow = (sub == 0xFFFF) ? 0 : sub * 16 + (row & 15);
    int srow = min(s0 + lrow, s1 - 1);
    __builtin_amdgcn_global_load_lds(
        (const unsigned int*)(sn + (size_t)srow * 128 + sj * 8),
        (unsigned int*)(dst + (o >> 1)), 16, 0, 0);
  }
}

// Pass 1: 16-row sub maxes. 1024 blocks XCD-decoded (8 slices/XCD).
// 32x32x16 MFMA, D[row=support][col=query]: lane = query (lane&31) x 16 rows.
__global__ __launch_bounds__(256, 4) void pass1_k(
    const ushort* __restrict__ qn, const ushort* __restrict__ sn,
    ushort* __restrict__ cm, int N) {
  __shared__ ushort st[2][CN * 128];
  const int tid = threadIdx.x;
  const int w = tid >> 6, lane = tid & 63;
  const int q32 = lane & 31, half = lane >> 5;
  const int L = blockIdx.x;             // 1024 = 8 xcd * (16 qtile * 8 slice)
  const int xcd = L & 7, i6 = L >> 3;
  const int qtile = i6 & 15;
  const int slice = (xcd << 3) | (i6 >> 4);
  const int qbase = qtile * BQ;
  const int SLICE = (N + NSLICES - 1) / NSLICES;  // 1563
  const int s0 = slice * SLICE;
  const int s1 = min(N, s0 + SLICE);
  const int nch = (s1 - s0 + CN - 1) / CN;  // 25 (24 for last slice)

  stage_lin(sn, &st[0][0], s0, s1, tid);

  // Query fragments (B operand): col = lane&31, k = half*8 + e per 16-k step.
  bf16x8 afr[8];
  {
    const int qrow = qbase + w * 32 + q32;
    #pragma unroll
    for (int t = 0; t < 8; ++t)
      afr[t] = *reinterpret_cast<const bf16x8*>(qn + (size_t)qrow * 128 + t * 16 + half * 8);
  }
  __syncthreads();

  int buf = 0;
  for (int ch = 0; ch < nch; ++ch) {
    const int cb = s0 + ch * CN;
    if (ch + 1 < nch) stage_lin(sn, &st[buf ^ 1][0], cb + CN, s1, tid);
    const ushort* stc = &st[buf][0];
    const bool lastch = (ch == nch - 1);

    f32x16 a0 = {0.f}, a1 = {0.f};
    #pragma unroll
    for (int r = 1; r < 16; ++r) { a0[r] = 0.f; a1[r] = 0.f; }
    const int r0 = q32;                  // A row within tile = lane&31
    #pragma unroll
    for (int t = 0; t < 8; ++t) {
      int jb = t * 2 + half;             // 16B block in row
      int cj = jb ^ (r0 & 15);           // rows r0 and r0+32 share (row&15)
      bf16x8 sf0 = *reinterpret_cast<const bf16x8*>(&stc[r0 * 128 + cj * 8]);
      bf16x8 sf1 = *reinterpret_cast<const bf16x8*>(&stc[(r0 + 32) * 128 + cj * 8]);
      a0 = __builtin_amdgcn_mfma_f32_32x32x16_bf16(sf0, afr[t], a0, 0, 0, 0);
      a1 = __builtin_amdgcn_mfma_f32_32x32x16_bf16(sf1, afr[t], a1, 0, 0, 0);
    }
    // lo/hi 16-row submaxes: rows = (r&3)+8*(r>>2)+(half<<2); r<8 -> rows 0..15,
    // r>=8 -> rows 16..31. Branch on lastch is HOISTED (uniform): fast path is
    // pure fmax (R15 lesson: per-element mask = +100 VALU ops/chunk, +29us).
    float v0lo, v0hi, v1lo, v1hi;
    if (!lastch) {
      v0lo = a0[0]; v0hi = a0[8]; v1lo = a1[0]; v1hi = a1[8];
      #pragma unroll
      for (int r = 1; r < 8; ++r) {
        v0lo = fmaxf(v0lo, a0[r]);
        v0hi = fmaxf(v0hi, a0[r + 8]);
        v1lo = fmaxf(v1lo, a1[r]);
        v1hi = fmaxf(v1hi, a1[r + 8]);
      }
    } else {
      v0lo = v0hi = v1lo = v1hi = -3.0e38f;
      #pragma unroll
      for (int r = 0; r < 8; ++r) {
        int row = (r & 3) + 8 * (r >> 2) + (half << 2);   // 0..15
        int rowh = row + 16;
        if (cb + row < s1) v0lo = fmaxf(v0lo, a0[r]);
        if (cb + rowh < s1) v0hi = fmaxf(v0hi, a0[r + 8]);
        if (cb + 32 + row < s1) v1lo = fmaxf(v1lo, a1[r]);
        if (cb + 32 + rowh < s1) v1hi = fmaxf(v1hi, a1[r + 8]);
      }
    }
    v0lo = fmaxf(v0lo, __shfl_xor(v0lo, 32));
    v0hi = fmaxf(v0hi, __shfl_xor(v0hi, 32));
    v1lo = fmaxf(v1lo, __shfl_xor(v1lo, 32));
    v1hi = fmaxf(v1hi, __shfl_xor(v1hi, 32));
    if (lane < 32) {                     // 32 lanes store 2B x 4 subs
      int q = qbase + w * 32 + q32;
      size_t e0 = ((size_t)(q >> 2) * NGS + slice * NSUB + ch * 4) * 4 + (q & 3);
      cm[e0] = f2bf_down(v0lo);          // sub ch*4+0: rows cb+0..15
      cm[e0 + 4] = f2bf_down(v0hi);      // sub ch*4+1: rows cb+16..31
      cm[e0 + 8] = f2bf_down(v1lo);      // sub ch*4+2: rows cb+32..47
      cm[e0 + 12] = f2bf_down(v1hi);     // sub ch*4+3: rows cb+48..63
    }
    __syncthreads();
    buf ^= 1;
  }

  // fill unwritten tail subs (nch < 25 on the last slice) with bf16 -inf
  const int miss = NSUB - nch * 4;
  for (int idx = tid; idx < miss * BQ; idx += 256) {
    int sub = nch * 4 + idx / BQ;
    int q = qbase + (idx % BQ);
    cm[((size_t)(q >> 2) * NGS + (size_t)(slice * NSUB + sub)) * 4 + (q & 3)] = 0xFF80;
  }
}

// thr[q] = 16th-largest of the 6400 sub-maxes, minus margin; zero cnt[q].
// 4 queries per 256-thread block (one per wave).
__global__ __launch_bounds__(256) void thr_k(const ushort* __restrict__ cm,
                                             float* __restrict__ thr,
                                             unsigned* __restrict__ cnt) {
  const int q = blockIdx.x * 4 + (threadIdx.x >> 6);
  const int lane = threadIdx.x & 63;
  const size_t base = (size_t)(q >> 2) * NGS * 4 + (q & 3);
  unsigned keys[NGS / 128];
  #pragma unroll
  for (int j = 0; j < NGS / 128; ++j) {
    unsigned k0 = bf2key(cm[base + (size_t)(lane + 128 * j) * 4]);
    unsigned k1 = bf2key(cm[base + (size_t)(lane + 64 + 128 * j) * 4]);
    keys[j] = k0 | (k1 << 16);
  }
  unsigned res = 0;
  for (int b = 15; b >= 0; --b) {
    unsigned t = res | (1u << b);
    int c = 0;
    #pragma unroll
    for (int j = 0; j < NGS / 128; ++j)
      c += (int)((keys[j] & 0xFFFFu) >= t) + (int)((keys[j] >> 16) >= t);
    #pragma unroll
    for (int o = 1; o < 64; o <<= 1) c += __shfl_xor(c, o);
    if (c >= 16) res = t;
  }
  if (lane == 0) {
    ushort b16 = (ushort)((res & 0x8000u) ? (res ^ 0x8000u) : (res ^ 0xFFFFu));
    thr[q] = __uint_as_float((unsigned)b16 << 16) - THR_MARGIN;
    cnt[q] = 0;
  }
}

// Pass 2: visit only hit 16-row subs (stored max >= thr), 4 per staged batch.
// 32x32x16 MFMA: lane = 1 query x 16 supports; thr per lane hoisted.
__global__ __launch_bounds__(256, 4) void pass2_k(
    const ushort* __restrict__ qn, const ushort* __restrict__ sn,
    const ushort* __restrict__ cm, const float* __restrict__ thr,
    unsigned* __restrict__ cnt, float2* __restrict__ candq, int N) {
  __shared__ ushort st[2][CN * 128];
  __shared__ float thr_l[BQ];
  __shared__ unsigned char hit[NSUB];
  __shared__ ushort slist[NSUB + 4];
  __shared__ int nhit_s;

  const int tid = threadIdx.x;
  const int w = tid >> 6, lane = tid & 63;
  const int q32 = lane & 31, half = lane >> 5;
  const int L = blockIdx.x;
  const int xcd = L & 7, i6 = L >> 3;
  const int qtile = i6 & 15;
  const int slice = (xcd << 3) | (i6 >> 4);
  const int qbase = qtile * BQ;
  const int SLICE = (N + NSLICES - 1) / NSLICES;
  const int s0 = slice * SLICE;
  const int s1 = min(N, s0 + SLICE);
  const int slen = s1 - s0;

  if (tid < BQ) thr_l[tid] = thr[qbase + tid];
  if (tid < NSUB) hit[tid] = 0;
  __syncthreads();

  // hit scan: thread (q = tid&127, parity = tid>>7) covers s = 2j+parity
  {
    int q = qbase + (tid & 127);
    int sh = tid >> 7;
    float tq = thr_l[tid & 127];
    size_t base = (size_t)(q >> 2) * NGS * 4 + (q & 3);
    for (int j = 0; j < NSUB / 2; ++j) {
      int s = 2 * j + sh;
      ushort b = cm[base + (size_t)(slice * NSUB + s) * 4];
      if (__uint_as_float((unsigned)b << 16) >= tq) hit[s] = 1;
    }
  }
  __syncthreads();
  // compact hit subs (wave 0; NSUB=100 -> two ballot rounds)
  if (tid < 64) {
    int total = 0;
    #pragma unroll
    for (int r = 0; r < 2; ++r) {
      int idx = r * 64 + tid;
      bool f = (idx < NSUB) && hit[idx];
      unsigned long long bm = __ballot(f);
      int pos = total + __popcll(bm & ((1ull << tid) - 1ull));
      if (f) slist[pos] = (ushort)idx;
      total += __popcll(bm);
    }
    if (tid == 0) {
      nhit_s = total;
      #pragma unroll
      for (int p = 0; p < 4; ++p) slist[total + p] = 0xFFFF;
    }
  }
  __syncthreads();
  const int nhit = nhit_s;
  if (nhit == 0) return;
  const int nb = (nhit + 3) >> 2;

  bf16x8 afr[8];
  {
    const int qrow = qbase + w * 32 + q32;
    #pragma unroll
    for (int t = 0; t < 8; ++t)
      afr[t] = *reinterpret_cast<const bf16x8*>(qn + (size_t)qrow * 128 + t * 16 + half * 8);
  }
  const float thrq = thr_l[w * 32 + q32];

  stage_list(sn, &st[0][0], &slist[0], s0, s1, tid);
  __syncthreads();

  int buf = 0;
  for (int b = 0; b < nb; ++b) {
    if (b + 1 < nb) stage_list(sn, &st[buf ^ 1][0], &slist[(b + 1) * 4], s0, s1, tid);
    const ushort* stc = &st[buf][0];

    f32x16 a0 = {0.f}, a1 = {0.f};
    #pragma unroll
    for (int r = 1; r < 16; ++r) { a0[r] = 0.f; a1[r] = 0.f; }
    const int r0 = q32;
    #pragma unroll
    for (int t = 0; t < 8; ++t) {
      int jb = t * 2 + half;
      int cj = jb ^ (r0 & 15);
      bf16x8 sf0 = *reinterpret_cast<const bf16x8*>(&stc[r0 * 128 + cj * 8]);
      bf16x8 sf1 = *reinterpret_cast<const bf16x8*>(&stc[(r0 + 32) * 128 + cj * 8]);
      a0 = __builtin_amdgcn_mfma_f32_32x32x16_bf16(sf0, afr[t], a0, 0, 0, 0);
      a1 = __builtin_amdgcn_mfma_f32_32x32x16_bf16(sf1, afr[t], a1, 0, 0, 0);
    }
    const int q = qbase + w * 32 + q32;
    // tile A = staged rows 0..31 (subs slist[4b], slist[4b+1]);
    // tile B = staged rows 32..63 (subs slist[4b+2], slist[4b+3]).
    #pragma unroll
    for (int tile = 0; tile < 2; ++tile) {
      unsigned hm = 0;
      #pragma unroll
      for (int r = 0; r < 16; ++r) {
        int row = (r & 3) + 8 * (r >> 2) + (half << 2);   // 0..31 within tile
        int sub = slist[b * 4 + tile * 2 + (row >> 4)];
        int lrow = row & 15;
        float sc = tile ? a1[r] : a0[r];
        if (sub != 0xFFFF && sub * 16 + lrow < slen && sc >= thrq) hm |= 1u << r;
      }
      if (__any(hm != 0u)) {
        #pragma unroll
        for (int r = 0; r < 16; ++r) {
          if (hm & (1u << r)) {
            int row = (r & 3) + 8 * (r >> 2) + (half << 2);
            int sub = slist[b * 4 + tile * 2 + (row >> 4)];
            int lrow = row & 15;
            float sc = tile ? a1[r] : a0[r];
            unsigned p = atomicAdd(&cnt[q], 1u);
            if (p < (unsigned)QCAP)
              candq[(size_t)q * QCAP + p] =
                  make_float2(sc, __int_as_float(s0 + sub * 16 + lrow));
          }
        }
      }
    }
    __syncthreads();
    buf ^= 1;
  }
}

// 4 queries per 256-thread block (one wave each): gather ~27 candidates,
// exact (f64) refine ALL, bitonic top-16 (tie: lower idx) -> weights -> out.
__global__ __launch_bounds__(256) void merge_refine_k(
    const float* __restrict__ query, const float* __restrict__ supports,
    const float* __restrict__ targets, const unsigned* __restrict__ cnt,
    const float2* __restrict__ candq, float* __restrict__ out) {
  const int W = threadIdx.x >> 6;
  const int q = blockIdx.x * 4 + W;
  const int lane = threadIdx.x & 63;
  __shared__ float qh_s[4][128];
  __shared__ float2 list[4][QCAP];
  __shared__ float2 refd[4][QCAP];

  int total = min((int)cnt[q], QCAP);
  if (lane < total) list[W][lane] = candq[(size_t)q * QCAP + lane];

  float2 qv = *reinterpret_cast<const float2*>(query + (size_t)q * 128 + lane * 2);
  double qss = (double)qv.x * qv.x + (double)qv.y * qv.y;
  #pragma unroll
  for (int o = 1; o < 64; o <<= 1) qss += __shfl_xor(qss, o);
  float qn1 = fmaxf((float)sqrt(qss), 1e-12f);
  qh_s[W][lane * 2] = qv.x / qn1;
  qh_s[W][lane * 2 + 1] = qv.y / qn1;
  __syncthreads();

  const int g16 = lane >> 4, m16 = lane & 15;
  float qh[8];
  #pragma unroll
  for (int d = 0; d < 8; ++d) qh[d] = qh_s[W][m16 * 8 + d];
  int rounds = (total + 3) >> 2;
  for (int r = 0; r < rounds; ++r) {
    int cc = r * 4 + g16;
    bool valid = cc < total;
    float2 ce = valid ? list[W][cc] : make_float2(0.f, __int_as_float(0));
    int sidx = __float_as_int(ce.y);
    float4 sa = *reinterpret_cast<const float4*>(supports + (size_t)sidx * 128 + m16 * 8);
    float4 sb = *reinterpret_cast<const float4*>(supports + (size_t)sidx * 128 + m16 * 8 + 4);
    float sv[8] = {sa.x, sa.y, sa.z, sa.w, sb.x, sb.y, sb.z, sb.w};
    double ss = 0.0, dt = 0.0;
    #pragma unroll
    for (int d = 0; d < 8; ++d) {
      ss += (double)sv[d] * sv[d];
      dt += (double)qh[d] * sv[d];
    }
    #pragma unroll
    for (int o = 1; o < 16; o <<= 1) {
      ss += __shfl_xor(ss, o);
      dt += __shfl_xor(dt, o);
    }
    if (m16 == 0 && valid) {
      float sn1 = fmaxf((float)sqrt(ss), 1e-12f);
      refd[W][cc] = make_float2((float)(1.0 - dt / (double)sn1), ce.y);
    }
  }
  __syncthreads();

  float dv = (lane < total) ? refd[W][lane].x : 3.0e38f;
  unsigned di = (lane < total) ? (unsigned)__float_as_int(refd[W][lane].y) : 0xFFFFFFFFu;
  bitonic64(dv, di, lane);  // ascending (d, idx): lanes 0..15 = top-16

  float wv = (lane < 16) ? 1.0f / (dv + 1e-8f) : 0.0f;
  float wsum = wv;
  #pragma unroll
  for (int o = 1; o < 64; o <<= 1) wsum += __shfl_xor(wsum, o);
  float acc[8];
  #pragma unroll
  for (int t = 0; t < 8; ++t) acc[t] = 0.f;
  if (lane < 16) {
    float wn = wv / wsum;
    const float* tp = targets + (size_t)di * 8;
    #pragma unroll
    for (int t = 0; t < 8; ++t) acc[t] = wn * tp[t];
  }
  #pragma unroll
  for (int o = 1; o < 16; o <<= 1) {
    #pragma unroll
    for (int t = 0; t < 8; ++t) acc[t] += __shfl_xor(acc[t], o);
  }
  if (lane == 0) {
    #pragma unroll
    for (int t = 0; t < 8; ++t) out[(size_t)q * 8 + t] = acc[t];
  }
}

extern "C" void kernel_launch(void* const* d_in, const int* in_sizes, int n_in,
                              void* d_out, int out_size, void* d_ws, size_t ws_size,
                              hipStream_t stream) {
  const float* query = (const float*)d_in[0];
  const float* supports = (const float*)d_in[1];
  const float* targets = (const float*)d_in[2];
  float* out = (float*)d_out;
  const int D = 128;
  const int B = in_sizes[0] / D;   // 2048
  const int N = in_sizes[1] / D;   // 100000

  char* ws = (char*)d_ws;
  size_t off = 0;
  ushort* sn = (ushort*)(ws + off); off += (size_t)N * D * 2;
  off = (off + 255) & ~(size_t)255;
  ushort* qn = (ushort*)(ws + off); off += (size_t)B * D * 2;
  off = (off + 255) & ~(size_t)255;
  ushort* cm = (ushort*)(ws + off); off += (size_t)B * NGS * 2;        // 26.2MB
  off = (off + 255) & ~(size_t)255;
  float* thr = (float*)(ws + off); off += (size_t)B * 4;
  off = (off + 255) & ~(size_t)255;
  unsigned* cnt = (unsigned*)(ws + off); off += (size_t)B * 4;
  off = (off + 255) & ~(size_t)255;
  float2* candq = (float2*)(ws + off); off += (size_t)B * QCAP * sizeof(float2);
  if (off > ws_size) return;

  hipLaunchKernelGGL(norm_rows_k, dim3((N + B + 3) / 4), dim3(256), 0, stream,
                     supports, query, sn, qn, N, B);
  int nblk = (B / BQ) * NSLICES;  // 1024
  hipLaunchKernelGGL(pass1_k, dim3(nblk), dim3(256), 0, stream, qn, sn, cm, N);
  hipLaunchKernelGGL(thr_k, dim3(B / 4), dim3(256), 0, stream, cm, thr, cnt);
  hipLaunchKernelGGL(pass2_k, dim3(nblk), dim3(256), 0, stream, qn, sn, cm, thr, cnt, candq, N);
  hipLaunchKernelGGL(merge_refine_k, dim3(B / 4), dim3(256), 0, stream, query, supports, targets, cnt, candq, out);
}